// Round 2
// baseline (111.961 us; speedup 1.0000x reference)
//
#include <hip/hip_runtime.h>
#include <hip/hip_cooperative_groups.h>

namespace cg = cooperative_groups;

// B=8, N=512, D=64, E=32
// ws layout (f32): src = ws[0 .. BNE), dst = ws[BNE .. 2*BNE)   (1 MB)
#define BNE (4096 * 32)

// Single cooperative kernel: 256 blocks x 512 threads = 8 waves/block,
// 1 block/CU -> all co-resident (coop launch validates this).
// Phase 1: projections (16 rows/block, x staged in LDS, be folded into src,
//          out = br init by blocks 0..7).
// grid.sync()
// Phase 2: delta[b,j] += sum_{i,e} relu(src[b,i,e]+dst[b,j,e]) * Wr[i*32+e].
//          block = (b, i-tile of 16); j = threadIdx; src/Wr rows are
//          wave-uniform (blockIdx + loop const) -> scalar-load path.
__global__ __launch_bounds__(512) void fused_kernel(
    const float* __restrict__ x, const float* __restrict__ We,
    const float* __restrict__ be, const float* __restrict__ Wr,
    const float* __restrict__ br, float* __restrict__ out,
    float* __restrict__ ws)
{
    __shared__ float xs[16 * 64];
    const int t   = threadIdx.x;           // 0..511
    const int blk = blockIdx.x;            // 0..255

    // ---------------- Phase 1: src/dst projections ----------------
    {
        const int r0 = blk << 4;           // 16 rows per block
        const float* __restrict__ xp = x + (size_t)r0 * 64;
        xs[t]       = xp[t];               // coalesced 4 KB/block
        xs[t + 512] = xp[t + 512];
        __syncthreads();

        const int w    = t >> 6;           // wave 0..7
        const int lane = t & 63;
        const int proj = lane >> 5;        // 0 = src, 1 = dst
        const int e    = lane & 31;
        const float* __restrict__ wcol = We + proj * (64 * 32) + e;  // coalesced

        #pragma unroll
        for (int rr = 0; rr < 2; ++rr) {   // 2 rows per wave
            const int lr = 2 * w + rr;
            float acc = 0.f;
            #pragma unroll
            for (int d = 0; d < 64; ++d)
                acc = fmaf(xs[lr * 64 + d], wcol[d * 32], acc);  // LDS broadcast
            if (proj == 0) acc += be[e];
            ws[(size_t)proj * BNE + (size_t)(r0 + lr) * 32 + e] = acc;
        }

        if (blk < 8) out[(blk << 9) + t] = br[0];
    }

    cg::this_grid().sync();

    // ---------------- Phase 2: edge accumulation ----------------
    const float* __restrict__ src = ws;
    const float* __restrict__ dst = ws + BNE;
    const int b  = blk >> 5;               // 0..7
    const int i0 = (blk & 31) << 4;        // i-tile of 16
    const int j  = t;                      // 0..511

    float dreg[32];
    const float4* __restrict__ dp =
        (const float4*)(dst + ((size_t)((b << 9) + j)) * 32);
    #pragma unroll
    for (int k = 0; k < 8; ++k) ((float4*)dreg)[k] = dp[k];   // 128 B dst row

    float a0 = 0.f, a1 = 0.f, a2 = 0.f, a3 = 0.f;

    #pragma unroll 2
    for (int ii = 0; ii < 16; ++ii) {
        const int i = i0 + ii;
        const float* __restrict__ srow = src + ((size_t)((b << 9) + i)) * 32; // uniform
        const float* __restrict__ wrow = Wr + (size_t)i * 32;                 // uniform
        #pragma unroll
        for (int e = 0; e < 32; e += 4) {
            a0 = fmaf(fmaxf(srow[e]     + dreg[e],     0.f), wrow[e],     a0);
            a1 = fmaf(fmaxf(srow[e + 1] + dreg[e + 1], 0.f), wrow[e + 1], a1);
            a2 = fmaf(fmaxf(srow[e + 2] + dreg[e + 2], 0.f), wrow[e + 2], a2);
            a3 = fmaf(fmaxf(srow[e + 3] + dreg[e + 3], 0.f), wrow[e + 3], a3);
        }
    }
    atomicAdd(&out[(b << 9) + j], (a0 + a1) + (a2 + a3));
}

extern "C" void kernel_launch(void* const* d_in, const int* in_sizes, int n_in,
                              void* d_out, int out_size, void* d_ws, size_t ws_size,
                              hipStream_t stream) {
    const float* x  = (const float*)d_in[0];   // (8,512,64)
    const float* We = (const float*)d_in[1];   // (128,32)
    const float* be = (const float*)d_in[2];   // (32,)
    const float* Wr = (const float*)d_in[3];   // (16384,1)
    const float* br = (const float*)d_in[4];   // (1,)
    float* out = (float*)d_out;                // (8,512,1) = 4096 floats
    float* ws  = (float*)d_ws;

    void* args[] = { (void*)&x, (void*)&We, (void*)&be, (void*)&Wr,
                     (void*)&br, (void*)&out, (void*)&ws };
    hipLaunchCooperativeKernel(reinterpret_cast<void*>(fused_kernel),
                               dim3(256), dim3(512), args, 0, stream);
}

// Round 3
// 72.955 us; speedup vs baseline: 1.5347x; 1.5347x over previous
//
#include <hip/hip_runtime.h>

// B=8, N=512, D=64, E=32
// ws layout: src = ws[0 .. 4096*32), dst = ws[4096*32 .. 2*4096*32)  (1 MB)
#define BNE (4096 * 32)

// Kernel 1: src/dst projections. One wave per row; x-row pointer uniform
// (blockIdx-only) -> scalar-load path. lane = (proj, e). Folds be into src,
// inits out = br.
__global__ __launch_bounds__(64) void proj_kernel(
    const float* __restrict__ x, const float* __restrict__ We,
    const float* __restrict__ be, const float* __restrict__ br,
    float* __restrict__ out, float* __restrict__ ws)
{
    const int lane = threadIdx.x;          // 0..63
    const int row  = blockIdx.x;           // 0..4095 = b*512 + i (uniform)
    const int proj = lane >> 5;            // 0 = src, 1 = dst
    const int e    = lane & 31;

    const float* __restrict__ xrow = x + (size_t)row * 64;        // uniform
    const float* __restrict__ wcol = We + proj * (64 * 32) + e;   // coalesced

    float acc = 0.0f;
    #pragma unroll
    for (int d = 0; d < 64; ++d)
        acc = fmaf(xrow[d], wcol[d * 32], acc);

    if (proj == 0) acc += be[e];

    ws[(size_t)proj * BNE + (size_t)row * 32 + e] = acc;

    if (blockIdx.x < 64) out[blockIdx.x * 64 + lane] = br[0];
}

// Kernel 2 (best measured config): delta[b,j] += sum_{i,e}
// relu(src[b,i,e]+dst[b,j,e]) * Wr[i*32+e]. Two j's per thread share each
// wave-uniform (src, Wr) scalar; i-tile = 8 -> grid (64,1,8) = 512 blocks.
// Probe: T ~= 6.6 us, VALUBusy 58%, hbm ~0 (L2-resident).
__global__ __launch_bounds__(256) void edge_kernel(
    const float* __restrict__ ws, const float* __restrict__ Wr,
    float* __restrict__ out)
{
    const float* __restrict__ src = ws;
    const float* __restrict__ dst = ws + BNE;

    const int b  = blockIdx.z;
    const int j0 = threadIdx.x;            // 0..255
    const int j1 = threadIdx.x + 256;      // 256..511
    const int i0 = blockIdx.x * 8;

    float d0[32], d1[32];
    const float4* __restrict__ dp0 = (const float4*)(dst + ((size_t)(b * 512 + j0)) * 32);
    const float4* __restrict__ dp1 = (const float4*)(dst + ((size_t)(b * 512 + j1)) * 32);
    #pragma unroll
    for (int k = 0; k < 8; ++k) {
        ((float4*)d0)[k] = dp0[k];
        ((float4*)d1)[k] = dp1[k];
    }

    float a00 = 0.f, a01 = 0.f, a10 = 0.f, a11 = 0.f;

    #pragma unroll 2
    for (int ii = 0; ii < 8; ++ii) {
        const int i = i0 + ii;
        const float* __restrict__ srow = src + ((size_t)(b * 512 + i)) * 32;  // uniform
        const float* __restrict__ wrow = Wr + (size_t)i * 32;                 // uniform
        #pragma unroll
        for (int e = 0; e < 32; e += 2) {
            const float s0 = srow[e],  s1 = srow[e + 1];
            const float w0 = wrow[e],  w1 = wrow[e + 1];
            a00 = fmaf(fmaxf(s0 + d0[e],     0.f), w0, a00);
            a01 = fmaf(fmaxf(s1 + d0[e + 1], 0.f), w1, a01);
            a10 = fmaf(fmaxf(s0 + d1[e],     0.f), w0, a10);
            a11 = fmaf(fmaxf(s1 + d1[e + 1], 0.f), w1, a11);
        }
    }

    atomicAdd(&out[b * 512 + j0], a00 + a01);
    atomicAdd(&out[b * 512 + j1], a10 + a11);
}

extern "C" void kernel_launch(void* const* d_in, const int* in_sizes, int n_in,
                              void* d_out, int out_size, void* d_ws, size_t ws_size,
                              hipStream_t stream) {
    const float* x  = (const float*)d_in[0];   // (8,512,64)
    const float* We = (const float*)d_in[1];   // (128,32)
    const float* be = (const float*)d_in[2];   // (32,)
    const float* Wr = (const float*)d_in[3];   // (16384,1)
    const float* br = (const float*)d_in[4];   // (1,)
    float* out = (float*)d_out;                // (8,512,1) = 4096 floats
    float* ws  = (float*)d_ws;

    proj_kernel<<<4096, 64, 0, stream>>>(x, We, be, br, out, ws);
    edge_kernel<<<dim3(64, 1, 8), 256, 0, stream>>>(ws, Wr, out);
}